// Round 10
// baseline (1689.137 us; speedup 1.0000x reference)
//
#include <hip/hip_runtime.h>

#define T_N 4096
#define B_N 64
#define I_N 128
#define H_N 128
#define BH  (B_N * H_N)

// ---------------------------------------------------------------------------
// Phase 1: xp = x @ W_ih^T + b_ih -> into out (in-place with phase 2).
// Unchanged from R2-R9 (~70 us).
// ---------------------------------------------------------------------------
__global__ __launch_bounds__(256) void xproj_kernel(
    const float* __restrict__ x, const float* __restrict__ Wih,
    const float* __restrict__ bih, float* __restrict__ xp)
{
    __shared__ float wt[I_N][H_N];   // wt[k][j] = Wih[j][k], 64 KB
    const int tid = threadIdx.x;

    {
        const float4* w4 = (const float4*)Wih;
        #pragma unroll
        for (int it = 0; it < 16; ++it) {
            int i = tid * 16 + it;          // 0..4095 float4s
            float4 v = w4[i];
            int r = i >> 5;                 // W row j
            int k = (i & 31) << 2;          // k base
            wt[k + 0][r] = v.x;
            wt[k + 1][r] = v.y;
            wt[k + 2][r] = v.z;
            wt[k + 3][r] = v.w;
        }
    }
    __syncthreads();

    const int  tx   = tid & 15;
    const int  ty   = tid >> 4;
    const long row0 = (long)blockIdx.x * 128;
    const float* xbase = x + (row0 + ty * 8) * I_N;

    float acc[8][8];
    #pragma unroll
    for (int r = 0; r < 8; ++r)
        #pragma unroll
        for (int c = 0; c < 8; ++c) acc[r][c] = 0.0f;

    #pragma unroll 2
    for (int k4 = 0; k4 < I_N / 4; ++k4) {
        float4 xv[8];
        #pragma unroll
        for (int r = 0; r < 8; ++r)
            xv[r] = *(const float4*)(xbase + r * I_N + k4 * 4);

        #pragma unroll
        for (int kk = 0; kk < 4; ++kk) {
            int k = k4 * 4 + kk;
            float4 w0 = *(const float4*)&wt[k][tx * 4];
            float4 w1 = *(const float4*)&wt[k][64 + tx * 4];
            #pragma unroll
            for (int r = 0; r < 8; ++r) {
                float xk = (kk == 0) ? xv[r].x : (kk == 1) ? xv[r].y
                         : (kk == 2) ? xv[r].z : xv[r].w;
                acc[r][0] = fmaf(xk, w0.x, acc[r][0]);
                acc[r][1] = fmaf(xk, w0.y, acc[r][1]);
                acc[r][2] = fmaf(xk, w0.z, acc[r][2]);
                acc[r][3] = fmaf(xk, w0.w, acc[r][3]);
                acc[r][4] = fmaf(xk, w1.x, acc[r][4]);
                acc[r][5] = fmaf(xk, w1.y, acc[r][5]);
                acc[r][6] = fmaf(xk, w1.z, acc[r][6]);
                acc[r][7] = fmaf(xk, w1.w, acc[r][7]);
            }
        }
    }

    float4 b0 = *(const float4*)(bih + tx * 4);
    float4 b1 = *(const float4*)(bih + 64 + tx * 4);
    #pragma unroll
    for (int r = 0; r < 8; ++r) {
        long row = row0 + ty * 8 + r;
        float4 o0, o1;
        o0.x = acc[r][0] + b0.x;  o0.y = acc[r][1] + b0.y;
        o0.z = acc[r][2] + b0.z;  o0.w = acc[r][3] + b0.w;
        o1.x = acc[r][4] + b1.x;  o1.y = acc[r][5] + b1.y;
        o1.z = acc[r][6] + b1.z;  o1.w = acc[r][7] + b1.w;
        *(float4*)(xp + row * H_N + tx * 4)      = o0;
        *(float4*)(xp + row * H_N + 64 + tx * 4) = o1;
    }
}

// ---------------------------------------------------------------------------
// Phase 2: scan, one block per batch (64 blocks x 256 threads = 4 waves).
// R10: p = lane&1 (k-chunk [64p,64p+64)), j = (lane>>1) + 32*wave.
// Per thread: 16 ds_read_b128 (2 broadcast addrs/inst, 4-bank offset ->
// conflict-free), 16 parallel DOT4s + 4-level tree, ONE DPP xor1 reduce
// round, tanh/ds_write/global-store exec-masked to p==0. vs R9: same FMA
// and ds_read issue per SIMD, but masked-op issue halves (4 waves not 8),
// DPP rounds 2->1, barrier syncs 4 waves. Global h-store moved pre-barrier
// into the ds_write -> lgkmcnt shadow.
// ---------------------------------------------------------------------------
__device__ __forceinline__ float tanh_pade(float x) {
    float u = x * x;
    float n = fmaf(u, u + 105.0f, 945.0f);              // u^2 + 105u + 945
    float d = fmaf(u, fmaf(15.0f, u, 420.0f), 945.0f);  // 15u^2 + 420u + 945
    float t = x * n * __builtin_amdgcn_rcpf(d);
    return fminf(1.0f, fmaxf(-1.0f, t));                // v_med3_f32
}

#define DPP_XOR1 0xB1   // quad_perm [1,0,3,2]

__device__ __forceinline__ float dpp_add_xor1(float v) {
    int s = __float_as_int(v);
    int r = __builtin_amdgcn_update_dpp(0, s, DPP_XOR1, 0xF, 0xF, true);
    return v + __int_as_float(r);
}

#define DOT4(W4, H4)                                                          \
    fmaf((W4).x, (H4).x, fmaf((W4).y, (H4).y,                                 \
    fmaf((W4).z, (H4).z, (W4).w * (H4).w)))

__global__ __launch_bounds__(256, 1) void scan_kernel(
    const float* __restrict__ Whh, const float* __restrict__ bhh,
    const float* __restrict__ h0, float* __restrict__ out)
{
    const int tid  = threadIdx.x;
    const int b    = blockIdx.x;
    const int lane = tid & 63;
    const int wv   = tid >> 6;                 // 0..3
    const int p    = lane & 1;                 // k-chunk [64p, 64p+64)
    const int j    = (lane >> 1) + 32 * wv;    // output row 0..127
    __shared__ float hbuf[2][2][68];           // [buf][k-chunk][64 + 4 pad]

    // W fragment: w[c] = Whh[j][64p + 4c .. +4), 64 floats
    float4 w[16];
    #pragma unroll
    for (int c = 0; c < 16; ++c)
        w[c] = *(const float4*)(Whh + j * H_N + 64 * p + 4 * c);

    const float bh = bhh[j];

    if (tid < H_N) hbuf[0][tid >> 6][tid & 63] = h0[b * H_N + tid];

    const float* xq = out + b * H_N + j;   // xp (t,b,j) at xq + t*BH
    float*       oq = out + b * H_N + j;

    float xv[4];
    #pragma unroll
    for (int d = 0; d < 4; ++d)
        xv[d] = xq[(size_t)d * BH];

    __syncthreads();

#define RNN_STEP(T0, D, CUR) do {                                             \
        const float4* hb = (const float4*)&hbuf[CUR][p][0];                   \
        float4 hv0 = hb[0],  hv1 = hb[1],  hv2 = hb[2],  hv3 = hb[3];         \
        float4 hv4 = hb[4],  hv5 = hb[5],  hv6 = hb[6],  hv7 = hb[7];         \
        float4 hv8 = hb[8],  hv9 = hb[9],  hvA = hb[10], hvB = hb[11];        \
        float4 hvC = hb[12], hvD = hb[13], hvE = hb[14], hvF = hb[15];        \
        float d0 = DOT4(w[0],  hv0) + DOT4(w[1],  hv1);                       \
        float d1 = DOT4(w[2],  hv2) + DOT4(w[3],  hv3);                       \
        float d2 = DOT4(w[4],  hv4) + DOT4(w[5],  hv5);                       \
        float d3 = DOT4(w[6],  hv6) + DOT4(w[7],  hv7);                       \
        float d4 = DOT4(w[8],  hv8) + DOT4(w[9],  hv9);                       \
        float d5 = DOT4(w[10], hvA) + DOT4(w[11], hvB);                       \
        float d6 = DOT4(w[12], hvC) + DOT4(w[13], hvD);                       \
        float d7 = DOT4(w[14], hvE) + DOT4(w[15], hvF);                       \
        float s = ((d0 + d1) + (d2 + d3)) + ((d4 + d5) + (d6 + d7));          \
        s = dpp_add_xor1(s);                                                  \
        if (p == 0) {                                                         \
            float hj = tanh_pade(s + xv[D] + bh);                             \
            hbuf[(CUR) ^ 1][j >> 6][j & 63] = hj;                             \
            oq[(size_t)(T0) * BH] = hj;                                       \
            if ((T0) == T_N - 1) oq[(size_t)T_N * BH] = hj;                   \
        }                                                                     \
        if ((T0) + 4 < T_N)                                                   \
            xv[D] = xq[(size_t)((T0) + 4) * BH];                              \
        asm volatile("s_waitcnt lgkmcnt(0)" ::: "memory");                    \
        __builtin_amdgcn_s_barrier();                                         \
        asm volatile("" ::: "memory");                                        \
    } while (0)

    for (int t = 0; t < T_N; t += 4) {
        RNN_STEP(t + 0, 0, 0);
        RNN_STEP(t + 1, 1, 1);
        RNN_STEP(t + 2, 2, 0);
        RNN_STEP(t + 3, 3, 1);
    }
#undef RNN_STEP
}

extern "C" void kernel_launch(void* const* d_in, const int* in_sizes, int n_in,
                              void* d_out, int out_size, void* d_ws, size_t ws_size,
                              hipStream_t stream) {
    const float* x   = (const float*)d_in[0];
    const float* h0  = (const float*)d_in[1];
    const float* Wih = (const float*)d_in[2];
    const float* Whh = (const float*)d_in[3];
    const float* bih = (const float*)d_in[4];
    const float* bhh = (const float*)d_in[5];
    float* out = (float*)d_out;

    xproj_kernel<<<dim3((T_N * B_N) / 128), 256, 0, stream>>>(x, Wih, bih, out);
    scan_kernel<<<dim3(B_N), 256, 0, stream>>>(Whh, bhh, h0, out);
}

// Round 11
// 1589.266 us; speedup vs baseline: 1.0628x; 1.0628x over previous
//
#include <hip/hip_runtime.h>

#define T_N 4096
#define B_N 64
#define I_N 128
#define H_N 128
#define BH  (B_N * H_N)

// ---------------------------------------------------------------------------
// Phase 1: xp = x @ W_ih^T + b_ih -> into out (in-place with phase 2).
// Unchanged from R2-R10 (~70 us).
// ---------------------------------------------------------------------------
__global__ __launch_bounds__(256) void xproj_kernel(
    const float* __restrict__ x, const float* __restrict__ Wih,
    const float* __restrict__ bih, float* __restrict__ xp)
{
    __shared__ float wt[I_N][H_N];   // wt[k][j] = Wih[j][k], 64 KB
    const int tid = threadIdx.x;

    {
        const float4* w4 = (const float4*)Wih;
        #pragma unroll
        for (int it = 0; it < 16; ++it) {
            int i = tid * 16 + it;          // 0..4095 float4s
            float4 v = w4[i];
            int r = i >> 5;                 // W row j
            int k = (i & 31) << 2;          // k base
            wt[k + 0][r] = v.x;
            wt[k + 1][r] = v.y;
            wt[k + 2][r] = v.z;
            wt[k + 3][r] = v.w;
        }
    }
    __syncthreads();

    const int  tx   = tid & 15;
    const int  ty   = tid >> 4;
    const long row0 = (long)blockIdx.x * 128;
    const float* xbase = x + (row0 + ty * 8) * I_N;

    float acc[8][8];
    #pragma unroll
    for (int r = 0; r < 8; ++r)
        #pragma unroll
        for (int c = 0; c < 8; ++c) acc[r][c] = 0.0f;

    #pragma unroll 2
    for (int k4 = 0; k4 < I_N / 4; ++k4) {
        float4 xv[8];
        #pragma unroll
        for (int r = 0; r < 8; ++r)
            xv[r] = *(const float4*)(xbase + r * I_N + k4 * 4);

        #pragma unroll
        for (int kk = 0; kk < 4; ++kk) {
            int k = k4 * 4 + kk;
            float4 w0 = *(const float4*)&wt[k][tx * 4];
            float4 w1 = *(const float4*)&wt[k][64 + tx * 4];
            #pragma unroll
            for (int r = 0; r < 8; ++r) {
                float xk = (kk == 0) ? xv[r].x : (kk == 1) ? xv[r].y
                         : (kk == 2) ? xv[r].z : xv[r].w;
                acc[r][0] = fmaf(xk, w0.x, acc[r][0]);
                acc[r][1] = fmaf(xk, w0.y, acc[r][1]);
                acc[r][2] = fmaf(xk, w0.z, acc[r][2]);
                acc[r][3] = fmaf(xk, w0.w, acc[r][3]);
                acc[r][4] = fmaf(xk, w1.x, acc[r][4]);
                acc[r][5] = fmaf(xk, w1.y, acc[r][5]);
                acc[r][6] = fmaf(xk, w1.z, acc[r][6]);
                acc[r][7] = fmaf(xk, w1.w, acc[r][7]);
            }
        }
    }

    float4 b0 = *(const float4*)(bih + tx * 4);
    float4 b1 = *(const float4*)(bih + 64 + tx * 4);
    #pragma unroll
    for (int r = 0; r < 8; ++r) {
        long row = row0 + ty * 8 + r;
        float4 o0, o1;
        o0.x = acc[r][0] + b0.x;  o0.y = acc[r][1] + b0.y;
        o0.z = acc[r][2] + b0.z;  o0.w = acc[r][3] + b0.w;
        o1.x = acc[r][4] + b1.x;  o1.y = acc[r][5] + b1.y;
        o1.z = acc[r][6] + b1.z;  o1.w = acc[r][7] + b1.w;
        *(float4*)(xp + row * H_N + tx * 4)      = o0;
        *(float4*)(xp + row * H_N + 64 + tx * 4) = o1;
    }
}

// ---------------------------------------------------------------------------
// Phase 2: scan, one block per batch (64 blocks x 1024 threads = 16 waves =
// 4 waves/SIMD). R11: one output per thread, k_split=8 with R3's lane-bit
// pattern p = (l&3)|((l>>1)&4) (bits {0,1,3}) so the 8-way reduce is DPP
// xor1 + xor2 + ror8 (pure VALU, intra-row); j = bits{2,4,5} + 8*wave.
// Per thread: 4 ds_read_b128 from the R3-verified conflict-free [8][20]
// layout, 4 DOT4 + 2 tree adds, 3 DPP rounds, masked tanh/ds_write/store
// on p==0. vs R9 (2 waves/SIMD): issue/SIMD ~236 -> ~310 cyc, but 4 waves
// interleave through the post-barrier ds_read latency, reduce/tanh chains,
// and barrier skew (the R9-vs-R10 lesson: TLP covers machinery).
// ---------------------------------------------------------------------------
__device__ __forceinline__ float tanh_pade(float x) {
    float u = x * x;
    float n = fmaf(u, u + 105.0f, 945.0f);              // u^2 + 105u + 945
    float d = fmaf(u, fmaf(15.0f, u, 420.0f), 945.0f);  // 15u^2 + 420u + 945
    float t = x * n * __builtin_amdgcn_rcpf(d);
    return fminf(1.0f, fmaxf(-1.0f, t));                // v_med3_f32
}

#define DPP_XOR1 0xB1   // quad_perm [1,0,3,2]
#define DPP_XOR2 0x4E   // quad_perm [2,3,0,1]
#define DPP_ROR8 0x128  // row_ror:8  (== xor8 within a 16-lane row)

__device__ __forceinline__ float dpp_add(float v, const int ctrl) {
    int s = __float_as_int(v);
    int r;
    switch (ctrl) {  // ctrl must be a literal
        case DPP_XOR1: r = __builtin_amdgcn_update_dpp(0, s, DPP_XOR1, 0xF, 0xF, true); break;
        case DPP_XOR2: r = __builtin_amdgcn_update_dpp(0, s, DPP_XOR2, 0xF, 0xF, true); break;
        default:       r = __builtin_amdgcn_update_dpp(0, s, DPP_ROR8, 0xF, 0xF, true); break;
    }
    return v + __int_as_float(r);
}

#define DOT4(W4, H4)                                                          \
    fmaf((W4).x, (H4).x, fmaf((W4).y, (H4).y,                                 \
    fmaf((W4).z, (H4).z, (W4).w * (H4).w)))

__global__ __launch_bounds__(1024, 1) void scan_kernel(
    const float* __restrict__ Whh, const float* __restrict__ bhh,
    const float* __restrict__ h0, float* __restrict__ out)
{
    const int tid  = threadIdx.x;
    const int b    = blockIdx.x;
    const int lane = tid & 63;
    const int wv   = tid >> 6;                                // 0..15
    const int p    = (lane & 3) | ((lane >> 1) & 4);          // 0..7, bits{0,1,3}
    const int jt   = ((lane >> 2) & 1) | ((lane >> 4) << 1);  // 0..7, bits{2,4,5}
    const int j    = jt + 8 * wv;                             // output row 0..127
    __shared__ float hbuf[2][8][20];  // [buf][k-chunk][16 + 4 pad] (R3 layout)

    // W fragment: w[c] = Whh[j][16p + 4c .. +4), 16 floats
    float4 w[4];
    #pragma unroll
    for (int c = 0; c < 4; ++c)
        w[c] = *(const float4*)(Whh + j * H_N + 16 * p + 4 * c);

    const float bh = bhh[j];

    if (tid < H_N) hbuf[0][tid >> 4][tid & 15] = h0[b * H_N + tid];

    const float* xq = out + b * H_N + j;   // xp (t,b,j) at xq + t*BH
    float*       oq = out + b * H_N + j;

    float xv[4];
    #pragma unroll
    for (int d = 0; d < 4; ++d)
        xv[d] = xq[(size_t)d * BH];

    __syncthreads();

#define RNN_STEP(T0, D, CUR) do {                                             \
        const float4* hb = (const float4*)&hbuf[CUR][p][0];                   \
        float4 hv0 = hb[0], hv1 = hb[1], hv2 = hb[2], hv3 = hb[3];            \
        float d01 = DOT4(w[0], hv0) + DOT4(w[1], hv1);                        \
        float d23 = DOT4(w[2], hv2) + DOT4(w[3], hv3);                        \
        float s = d01 + d23;                                                  \
        s = dpp_add(s, DPP_XOR1);                                             \
        s = dpp_add(s, DPP_XOR2);                                             \
        s = dpp_add(s, DPP_ROR8);                                             \
        float hj;                                                             \
        if (p == 0) {                                                         \
            hj = tanh_pade(s + xv[D] + bh);                                   \
            hbuf[(CUR) ^ 1][j >> 4][j & 15] = hj;                             \
        }                                                                     \
        if ((T0) + 4 < T_N)                                                   \
            xv[D] = xq[(size_t)((T0) + 4) * BH];                              \
        asm volatile("s_waitcnt lgkmcnt(0)" ::: "memory");                    \
        __builtin_amdgcn_s_barrier();                                         \
        if (p == 0) {                                                         \
            oq[(size_t)(T0) * BH] = hj;                                       \
            if ((T0) == T_N - 1) oq[(size_t)T_N * BH] = hj;                   \
        }                                                                     \
        asm volatile("" ::: "memory");                                        \
    } while (0)

    for (int t = 0; t < T_N; t += 4) {
        RNN_STEP(t + 0, 0, 0);
        RNN_STEP(t + 1, 1, 1);
        RNN_STEP(t + 2, 2, 0);
        RNN_STEP(t + 3, 3, 1);
    }
#undef RNN_STEP
}

extern "C" void kernel_launch(void* const* d_in, const int* in_sizes, int n_in,
                              void* d_out, int out_size, void* d_ws, size_t ws_size,
                              hipStream_t stream) {
    const float* x   = (const float*)d_in[0];
    const float* h0  = (const float*)d_in[1];
    const float* Wih = (const float*)d_in[2];
    const float* Whh = (const float*)d_in[3];
    const float* bih = (const float*)d_in[4];
    const float* bhh = (const float*)d_in[5];
    float* out = (float*)d_out;

    xproj_kernel<<<dim3((T_N * B_N) / 128), 256, 0, stream>>>(x, Wih, bih, out);
    scan_kernel<<<dim3(B_N), 1024, 0, stream>>>(Whh, bhh, h0, out);
}

// Round 12
// 1554.725 us; speedup vs baseline: 1.0865x; 1.0222x over previous
//
#include <hip/hip_runtime.h>

#define T_N 4096
#define B_N 64
#define I_N 128
#define H_N 128
#define BH  (B_N * H_N)
#define NB2 16     // batches per scan block (MFMA M-dim)
#define NPAD 136   // fp16 row stride for h_lds (128 + 8 pad)

typedef _Float16 half8 __attribute__((ext_vector_type(8)));
typedef _Float16 half4 __attribute__((ext_vector_type(4)));
typedef float    f32x4 __attribute__((ext_vector_type(4)));

// ---------------------------------------------------------------------------
// Phase 1: xp = x @ W_ih^T + b_ih -> into out (in-place with phase 2).
// Unchanged from R2-R11 (~70 us).
// ---------------------------------------------------------------------------
__global__ __launch_bounds__(256) void xproj_kernel(
    const float* __restrict__ x, const float* __restrict__ Wih,
    const float* __restrict__ bih, float* __restrict__ xp)
{
    __shared__ float wt[I_N][H_N];   // wt[k][j] = Wih[j][k], 64 KB
    const int tid = threadIdx.x;

    {
        const float4* w4 = (const float4*)Wih;
        #pragma unroll
        for (int it = 0; it < 16; ++it) {
            int i = tid * 16 + it;          // 0..4095 float4s
            float4 v = w4[i];
            int r = i >> 5;                 // W row j
            int k = (i & 31) << 2;          // k base
            wt[k + 0][r] = v.x;
            wt[k + 1][r] = v.y;
            wt[k + 2][r] = v.z;
            wt[k + 3][r] = v.w;
        }
    }
    __syncthreads();

    const int  tx   = tid & 15;
    const int  ty   = tid >> 4;
    const long row0 = (long)blockIdx.x * 128;
    const float* xbase = x + (row0 + ty * 8) * I_N;

    float acc[8][8];
    #pragma unroll
    for (int r = 0; r < 8; ++r)
        #pragma unroll
        for (int c = 0; c < 8; ++c) acc[r][c] = 0.0f;

    #pragma unroll 2
    for (int k4 = 0; k4 < I_N / 4; ++k4) {
        float4 xv[8];
        #pragma unroll
        for (int r = 0; r < 8; ++r)
            xv[r] = *(const float4*)(xbase + r * I_N + k4 * 4);

        #pragma unroll
        for (int kk = 0; kk < 4; ++kk) {
            int k = k4 * 4 + kk;
            float4 w0 = *(const float4*)&wt[k][tx * 4];
            float4 w1 = *(const float4*)&wt[k][64 + tx * 4];
            #pragma unroll
            for (int r = 0; r < 8; ++r) {
                float xk = (kk == 0) ? xv[r].x : (kk == 1) ? xv[r].y
                         : (kk == 2) ? xv[r].z : xv[r].w;
                acc[r][0] = fmaf(xk, w0.x, acc[r][0]);
                acc[r][1] = fmaf(xk, w0.y, acc[r][1]);
                acc[r][2] = fmaf(xk, w0.z, acc[r][2]);
                acc[r][3] = fmaf(xk, w0.w, acc[r][3]);
                acc[r][4] = fmaf(xk, w1.x, acc[r][4]);
                acc[r][5] = fmaf(xk, w1.y, acc[r][5]);
                acc[r][6] = fmaf(xk, w1.z, acc[r][6]);
                acc[r][7] = fmaf(xk, w1.w, acc[r][7]);
            }
        }
    }

    float4 b0 = *(const float4*)(bih + tx * 4);
    float4 b1 = *(const float4*)(bih + 64 + tx * 4);
    #pragma unroll
    for (int r = 0; r < 8; ++r) {
        long row = row0 + ty * 8 + r;
        float4 o0, o1;
        o0.x = acc[r][0] + b0.x;  o0.y = acc[r][1] + b0.y;
        o0.z = acc[r][2] + b0.z;  o0.w = acc[r][3] + b0.w;
        o1.x = acc[r][4] + b1.x;  o1.y = acc[r][5] + b1.y;
        o1.z = acc[r][6] + b1.z;  o1.w = acc[r][7] + b1.w;
        *(float4*)(xp + row * H_N + tx * 4)      = o0;
        *(float4*)(xp + row * H_N + 64 + tx * 4) = o1;
    }
}

// ---------------------------------------------------------------------------
// Phase 2 (R12): MFMA scan. 4 blocks x 16 batches, 512 threads = 8 waves.
// Per step: D[j][batch] = W(fp16,static VGPR) x h^T(fp16,LDS) via 4x
// mfma_f32_16x16x32_f16 per wave (wave owns j-range [16*wv,16*wv+16)).
// Orientation chosen so the m89-verified C/D layout (col=lane&15=batch,
// row=4*(lane>>4)+reg=j) gives each lane 4 CONSECUTIVE j for one batch:
// epilogue = float4 xp load + 4x tanh + ds_write_b64 (fp16 h) + float4
// out store. A/B frag k-grouping assumed standard: lane holds 8 consecutive
// k at kbase = 8*(lane>>4); A row = lane&15 (=j), B col = lane&15 (=batch).
// h double-buffered [2][16][136] fp16 (row 272B: balanced banks).
// ---------------------------------------------------------------------------
__device__ __forceinline__ float tanh_pade(float x) {
    float u = x * x;
    float n = fmaf(u, u + 105.0f, 945.0f);              // u^2 + 105u + 945
    float d = fmaf(u, fmaf(15.0f, u, 420.0f), 945.0f);  // 15u^2 + 420u + 945
    float t = x * n * __builtin_amdgcn_rcpf(d);
    return fminf(1.0f, fmaxf(-1.0f, t));                // v_med3_f32
}

__global__ __launch_bounds__(512, 1) void scan_mfma(
    const float* __restrict__ Whh, const float* __restrict__ bhh,
    const float* __restrict__ h0, float* __restrict__ out)
{
    const int tid  = threadIdx.x;
    const int lane = tid & 63;
    const int wv   = tid >> 6;              // 0..7
    const int r16  = lane & 15;             // batch col (B/C) ; j row (A)
    const int kg   = lane >> 4;             // 0..3 k-group
    const int jb   = wv * 16;               // wave j-base
    const int b    = blockIdx.x * NB2 + r16;  // global batch for xp/out

    __shared__ __align__(16) _Float16 hbuf[2][NB2][NPAD];

    // A-frags: W[jb + r16][32m + 8kg .. +8], fp32 -> fp16, resident forever.
    half8 afrag[4];
    #pragma unroll
    for (int m = 0; m < 4; ++m) {
        const float* wp = Whh + (size_t)(jb + r16) * H_N + m * 32 + kg * 8;
        float4 wa = *(const float4*)wp;
        float4 wb = *(const float4*)(wp + 4);
        afrag[m][0] = (_Float16)wa.x; afrag[m][1] = (_Float16)wa.y;
        afrag[m][2] = (_Float16)wa.z; afrag[m][3] = (_Float16)wa.w;
        afrag[m][4] = (_Float16)wb.x; afrag[m][5] = (_Float16)wb.y;
        afrag[m][6] = (_Float16)wb.z; afrag[m][7] = (_Float16)wb.w;
    }

    // Lane's 4 outputs are j = jb + 4kg + {0..3} (consecutive).
    const float4 bh4 = *(const float4*)(bhh + jb + 4 * kg);

    // Stage h0 -> hbuf[0][batch][j] (fp16).
    for (int i = tid; i < NB2 * H_N; i += 512) {
        int bt = i >> 7, j = i & 127;
        hbuf[0][bt][j] = (_Float16)h0[(size_t)(blockIdx.x * NB2 + bt) * H_N + j];
    }

    const float* xq = out + (size_t)b * H_N + jb + 4 * kg;
    float*       oq = out + (size_t)b * H_N + jb + 4 * kg;

    float4 xv[4];
    #pragma unroll
    for (int d = 0; d < 4; ++d)
        xv[d] = *(const float4*)(xq + (size_t)d * BH);

    __syncthreads();

#define STEP(T0, D, CUR, NXT) do {                                            \
        const _Float16* hb = &hbuf[CUR][r16][0];                              \
        half8 bf0 = *(const half8*)(hb + kg * 8);                             \
        half8 bf1 = *(const half8*)(hb + 32 + kg * 8);                        \
        half8 bf2 = *(const half8*)(hb + 64 + kg * 8);                        \
        half8 bf3 = *(const half8*)(hb + 96 + kg * 8);                        \
        f32x4 acc0 = {0.f, 0.f, 0.f, 0.f};                                    \
        f32x4 acc1 = {0.f, 0.f, 0.f, 0.f};                                    \
        acc0 = __builtin_amdgcn_mfma_f32_16x16x32_f16(afrag[0], bf0, acc0, 0, 0, 0); \
        acc1 = __builtin_amdgcn_mfma_f32_16x16x32_f16(afrag[1], bf1, acc1, 0, 0, 0); \
        acc0 = __builtin_amdgcn_mfma_f32_16x16x32_f16(afrag[2], bf2, acc0, 0, 0, 0); \
        acc1 = __builtin_amdgcn_mfma_f32_16x16x32_f16(afrag[3], bf3, acc1, 0, 0, 0); \
        float4 hv;                                                            \
        hv.x = tanh_pade(acc0[0] + acc1[0] + xv[D].x + bh4.x);                \
        hv.y = tanh_pade(acc0[1] + acc1[1] + xv[D].y + bh4.y);                \
        hv.z = tanh_pade(acc0[2] + acc1[2] + xv[D].z + bh4.z);                \
        hv.w = tanh_pade(acc0[3] + acc1[3] + xv[D].w + bh4.w);                \
        half4 hh;                                                             \
        hh[0] = (_Float16)hv.x; hh[1] = (_Float16)hv.y;                       \
        hh[2] = (_Float16)hv.z; hh[3] = (_Float16)hv.w;                       \
        *(half4*)&hbuf[NXT][r16][jb + 4 * kg] = hh;                           \
        *(float4*)(oq + (size_t)(T0) * BH) = hv;                              \
        if ((T0) == T_N - 1) *(float4*)(oq + (size_t)T_N * BH) = hv;          \
        if ((T0) + 4 < T_N)                                                   \
            xv[D] = *(const float4*)(xq + (size_t)((T0) + 4) * BH);           \
        asm volatile("s_waitcnt lgkmcnt(0)" ::: "memory");                    \
        __builtin_amdgcn_s_barrier();                                         \
        asm volatile("" ::: "memory");                                        \
    } while (0)

    for (int t = 0; t < T_N; t += 4) {
        STEP(t + 0, 0, 0, 1);
        STEP(t + 1, 1, 1, 0);
        STEP(t + 2, 2, 0, 1);
        STEP(t + 3, 3, 1, 0);
    }
#undef STEP
}

extern "C" void kernel_launch(void* const* d_in, const int* in_sizes, int n_in,
                              void* d_out, int out_size, void* d_ws, size_t ws_size,
                              hipStream_t stream) {
    const float* x   = (const float*)d_in[0];
    const float* h0  = (const float*)d_in[1];
    const float* Wih = (const float*)d_in[2];
    const float* Whh = (const float*)d_in[3];
    const float* bih = (const float*)d_in[4];
    const float* bhh = (const float*)d_in[5];
    float* out = (float*)d_out;

    xproj_kernel<<<dim3((T_N * B_N) / 128), 256, 0, stream>>>(x, Wih, bih, out);
    scan_mfma<<<dim3(B_N / NB2), 512, 0, stream>>>(Whh, bhh, h0, out);
}